// Round 10
// baseline (293.873 us; speedup 1.0000x reference)
//
#include <hip/hip_runtime.h>
#include <hip/hip_bf16.h>
#include <math.h>

// GAT forward: N=100000, E=1.6M (row sorted = dest), F_IN=128, F_OUT=32,
// HEADS=8, ALPHA=0.2. Output [N, 256] f32.
//
// Round 10 (bisect after unexplained R9 fail):
//  - EXACT R8 pipeline (prep0 / aproj_conv / feat_gemm_mfma / gat_scatter),
//    which passed at 290 us.
//  - ONE change: scatter pass-2 loops get #pragma unroll 4 (4 independent
//    dwordx2 gathers in flight) to attack the memory-latency bound R8
//    exposed (VALUBusy 39%, dur flat vs R6). No new index math, no new asm.

#define F_IN   128
#define F_ALL  256   // HEADS * F_OUT
#define HEADS  8
#define F_OUT  32
#define ALPHA  0.2f

using f32x4  = __attribute__((ext_vector_type(4))) float;
using bf16x8 = __attribute__((ext_vector_type(8))) short;

static __device__ __forceinline__ unsigned short f32_to_bf16(float f) {
  union { float f; unsigned u; } v; v.f = f;
  unsigned r = v.u + 0x7FFF + ((v.u >> 16) & 1);   // RNE
  return (unsigned short)(r >> 16);
}
static __device__ __forceinline__ unsigned cvt_pk_bf16(float lo, float hi) {
  unsigned r;
  asm("v_cvt_pk_bf16_f32 %0, %1, %2" : "=v"(r) : "v"(lo), "v"(hi));
  return r;
}
static __device__ __forceinline__ float bf16_lo(unsigned d) {
  return __uint_as_float(d << 16);
}
static __device__ __forceinline__ float bf16_hi(unsigned d) {
  return __uint_as_float(d & 0xffff0000u);
}

// ---- 0) prep0: ws/wn = W@att (f32), Wt[256][128] bf16, CSR ptr ----
__global__ __launch_bounds__(256) void prep0(const float* __restrict__ kern,
                                             const float* __restrict__ att_s,
                                             const float* __restrict__ att_n,
                                             const int* __restrict__ row,
                                             unsigned short* __restrict__ Wt,
                                             float* __restrict__ ws,
                                             float* __restrict__ wn,
                                             int* __restrict__ ptr,
                                             int N, int E) {
  int id = blockIdx.x * 256 + threadIdx.x;
  if (id < 2 * HEADS * F_IN) {      // ws[h][k], wn[h][k] (f32, exact)
    int which = id >> 10;
    int hk = id & 1023;
    int h = hk >> 7, k = hk & 127;
    const float* att = which ? att_n : att_s;
    float s = 0.f;
#pragma unroll
    for (int f = 0; f < F_OUT; ++f)
      s += kern[(size_t)h * (F_IN * F_OUT) + k * F_OUT + f] * att[h * F_OUT + f];
    (which ? wn : ws)[hk] = s;
  } else if (id < 4096) {           // Wt[c][k] = kern[c>>5][k][c&31], 16/thread
    int base = (id - 2048) * 16;
#pragma unroll
    for (int i = base; i < base + 16; ++i) {
      int c = i >> 7, k = i & 127;
      Wt[i] = f32_to_bf16(kern[(size_t)(c >> 5) * (F_IN * F_OUT) + k * F_OUT + (c & 31)]);
    }
  }
  if (id <= N) {                    // CSR offsets via binary search
    int lo = 0, hi = E;
    while (lo < hi) {
      int mid = (lo + hi) >> 1;
      if (row[mid] < id) lo = mid + 1; else hi = mid;
    }
    ptr[id] = lo;
  }
}

// ---- 1) aproj_conv: a_s/a_n (exact f32) + x->bf16, x read once ----
// wave per node: lane l = q*16+o; q = k-quarter (32 floats), o = output 0..15
__global__ __launch_bounds__(256) void aproj_conv(const float* __restrict__ x,
                                                  const float* __restrict__ ws,
                                                  const float* __restrict__ wn,
                                                  unsigned short* __restrict__ xb,
                                                  float* __restrict__ a_s,
                                                  float* __restrict__ a_n, int N) {
  const int t = threadIdx.x;
  const int l = t & 63;
  const int o = l & 15, q = l >> 4;
  const int wid = (blockIdx.x * 256 + t) >> 6;
  const int nw  = (gridDim.x * 256) >> 6;

  const float* wrow = (o < 8 ? ws + o * F_IN : wn + (o - 8) * F_IN) + q * 32;
  float4 wv[8];
#pragma unroll
  for (int i = 0; i < 8; i++) wv[i] = reinterpret_cast<const float4*>(wrow)[i];

  for (int n = wid; n < N; n += nw) {
    const float4* xr = reinterpret_cast<const float4*>(x + (size_t)n * F_IN + q * 32);
    float acc = 0.f;
#pragma unroll
    for (int i = 0; i < 8; i++) {
      float4 xv = xr[i];
      acc += xv.x * wv[i].x + xv.y * wv[i].y + xv.z * wv[i].z + xv.w * wv[i].w;
    }
    acc += __shfl_xor(acc, 16);
    acc += __shfl_xor(acc, 32);
    if (l < 16) {
      if (o < 8) a_s[n * HEADS + o] = acc;
      else       a_n[n * HEADS + (o - 8)] = acc;
    }
    // conversion: q==0 lanes own chunk o (32B, L1-hot after the dot loads)
    if (q == 0) {
      const float4* xc = reinterpret_cast<const float4*>(x + (size_t)n * F_IN + o * 8);
      float4 y0 = xc[0], y1 = xc[1];
      uint4 pk;
      pk.x = cvt_pk_bf16(y0.x, y0.y);
      pk.y = cvt_pk_bf16(y0.z, y0.w);
      pk.z = cvt_pk_bf16(y1.x, y1.y);
      pk.w = cvt_pk_bf16(y1.z, y1.w);
      *reinterpret_cast<uint4*>(xb + (size_t)n * F_IN + o * 8) = pk;
    }
  }
}

// ---- 2) feat = xb @ Wt^T via MFMA (swapped operands, packed stores) ----
__global__ __launch_bounds__(256) void feat_gemm_mfma(
    const unsigned short* __restrict__ xb,   // [N][128] bf16
    const unsigned short* __restrict__ Wt,   // [256][128] bf16
    unsigned short* __restrict__ featb,      // [N][256] bf16
    int N) {
  const int t  = threadIdx.x;
  const int w  = t >> 6;        // wave 0..3
  const int l  = t & 63;
  const int lr = l & 15;        // node within 16-tile (D col)
  const int lq = l >> 4;        // k-slice / D row group
  const int n0 = blockIdx.x * 64 + w * 16;

  f32x4 acc[16];
#pragma unroll
  for (int ct = 0; ct < 16; ++ct) acc[ct] = (f32x4){0.f, 0.f, 0.f, 0.f};

  int ar = n0 + lr; if (ar >= N) ar = N - 1;
  const unsigned short* xrow = xb + (size_t)ar * F_IN + lq * 8;
  bf16x8 xfr[4];
#pragma unroll
  for (int kc = 0; kc < 4; ++kc)
    xfr[kc] = *reinterpret_cast<const bf16x8*>(xrow + kc * 32);

#pragma unroll
  for (int ct = 0; ct < 16; ++ct) {
    const unsigned short* wrow = Wt + (size_t)(ct * 16 + lr) * F_IN + lq * 8;
#pragma unroll
    for (int kc = 0; kc < 4; ++kc) {
      bf16x8 wfr = *reinterpret_cast<const bf16x8*>(wrow + kc * 32);
      acc[ct] = __builtin_amdgcn_mfma_f32_16x16x32_bf16(wfr, xfr[kc], acc[ct], 0, 0, 0);
    }
  }
  // lane owns node ar, cols ct*16 + lq*4 + r: packed dwordx2 stores
  if (n0 + lr < N) {
    unsigned short* frow = featb + (size_t)ar * F_ALL + lq * 4;
#pragma unroll
    for (int ct = 0; ct < 16; ++ct) {
      uint2 v;
      v.x = cvt_pk_bf16(acc[ct][0], acc[ct][1]);
      v.y = cvt_pk_bf16(acc[ct][2], acc[ct][3]);
      *reinterpret_cast<uint2*>(frow + ct * 16) = v;
    }
  }
}

// ---- 3) per-node softmax + SpMM: 128 thr/node, 16-lane head group,
//         lane = (parity p, slot q) -> dwordx2 = 4 features of own edge ----
__global__ __launch_bounds__(256) void gat_scatter(
    const unsigned short* __restrict__ featb,
    const float* __restrict__ a_s, const float* __restrict__ a_n,
    const int* __restrict__ col, const int* __restrict__ ptr,
    const float* __restrict__ biases, float* __restrict__ out, int N) {
  const int t  = threadIdx.x;
  const int n  = blockIdx.x * 2 + (t >> 7);   // 2 nodes per block
  if (n >= N) return;
  const int tl = t & 127;
  const int g  = tl >> 5;                     // head pair 0..3
  const int hh = (tl >> 4) & 1;
  const int h  = g * 2 + hh;                  // head 0..7
  const int s  = tl & 15;                     // lane within head group
  const int p  = s >> 3;                      // edge parity
  const int q  = s & 7;                       // feature slot (4 feats)
  const int obase = h * F_OUT + q * 4;

  const int start = ptr[n];
  const int deg   = ptr[n + 1] - start;

  if (deg == 0) {
    if (p == 0)
      *reinterpret_cast<float4*>(&out[(size_t)n * F_ALL + obase]) =
          *reinterpret_cast<const float4*>(&biases[obase]);
    return;
  }

  const float as = a_s[n * HEADS + h];
  const unsigned* fu32 = reinterpret_cast<const unsigned*>(featb);
  const size_t dbase = (size_t)h * 16 + q * 2;

  if (deg <= 32) {
    // pass 1: lane s owns edges s and s+16 (within this head's 16-lane group)
    int c1 = 0, c2 = 0;
    float ex1 = 0.f, ex2 = 0.f;
    if (s < deg) {
      c1 = col[start + s];
      float v = as + a_n[c1 * HEADS + h];
      v = v > 0.f ? v : ALPHA * v;
      ex1 = __expf(v);
    }
    if (s + 16 < deg) {
      c2 = col[start + s + 16];
      float v = as + a_n[c2 * HEADS + h];
      v = v > 0.f ? v : ALPHA * v;
      ex2 = __expf(v);
    }
    float sm = ex1 + ex2;
#pragma unroll
    for (int m = 1; m <= 8; m <<= 1) sm += __shfl_xor(sm, m);
    const float inv = 1.0f / sm;

    // pass 2: parity p handles edges e+p; dwordx2 = 4 features.
    // unroll 4 -> 4 independent gathers in flight (latency hiding).
    float a0 = 0.f, a1 = 0.f, a2 = 0.f, a3 = 0.f;
    const int d1 = ((deg < 16 ? deg : 16) + 1) & ~1;
#pragma unroll 4
    for (int e = 0; e < d1; e += 2) {
      int   c = __shfl(c1,  e + p, 16);
      float w = __shfl(ex1, e + p, 16);
      uint2 d = *reinterpret_cast<const uint2*>(fu32 + (size_t)c * 128 + dbase);
      a0 = fmaf(w, bf16_lo(d.x), a0);
      a1 = fmaf(w, bf16_hi(d.x), a1);
      a2 = fmaf(w, bf16_lo(d.y), a2);
      a3 = fmaf(w, bf16_hi(d.y), a3);
    }
    if (deg > 16) {
      const int d2 = (deg - 16 + 1) & ~1;
#pragma unroll 4
      for (int e = 0; e < d2; e += 2) {
        int   c = __shfl(c2,  e + p, 16);
        float w = __shfl(ex2, e + p, 16);
        uint2 d = *reinterpret_cast<const uint2*>(fu32 + (size_t)c * 128 + dbase);
        a0 = fmaf(w, bf16_lo(d.x), a0);
        a1 = fmaf(w, bf16_hi(d.x), a1);
        a2 = fmaf(w, bf16_lo(d.y), a2);
        a3 = fmaf(w, bf16_hi(d.y), a3);
      }
    }
    // merge parities (xor bit 3 of s), p==0 writes float4
    a0 += __shfl_xor(a0, 8);
    a1 += __shfl_xor(a1, 8);
    a2 += __shfl_xor(a2, 8);
    a3 += __shfl_xor(a3, 8);
    if (p == 0) {
      const float4 bv = *reinterpret_cast<const float4*>(&biases[obase]);
      float4 o = {a0 * inv + bv.x, a1 * inv + bv.y, a2 * inv + bv.z, a3 * inv + bv.w};
      *reinterpret_cast<float4*>(&out[(size_t)n * F_ALL + obase]) = o;
    }
    return;
  }

  // ---- slow path (deg > 32, ~1e-4 of nodes) ----
  float sm = 0.f;
  for (int e = s; e < deg; e += 16) {
    int c = col[start + e];
    float v = as + a_n[c * HEADS + h];
    v = v > 0.f ? v : ALPHA * v;
    sm += __expf(v);
  }
#pragma unroll
  for (int m = 1; m <= 8; m <<= 1) sm += __shfl_xor(sm, m);
  const float inv = 1.0f / sm;

  float a0 = 0.f, a1 = 0.f, a2 = 0.f, a3 = 0.f;
#pragma unroll 4
  for (int e = p; e < deg; e += 2) {
    int c = col[start + e];
    float v = as + a_n[c * HEADS + h];
    v = v > 0.f ? v : ALPHA * v;
    float w = __expf(v);
    uint2 d = *reinterpret_cast<const uint2*>(fu32 + (size_t)c * 128 + dbase);
    a0 = fmaf(w, bf16_lo(d.x), a0);
    a1 = fmaf(w, bf16_hi(d.x), a1);
    a2 = fmaf(w, bf16_lo(d.y), a2);
    a3 = fmaf(w, bf16_hi(d.y), a3);
  }
  a0 += __shfl_xor(a0, 8);
  a1 += __shfl_xor(a1, 8);
  a2 += __shfl_xor(a2, 8);
  a3 += __shfl_xor(a3, 8);
  if (p == 0) {
    const float4 bv = *reinterpret_cast<const float4*>(&biases[obase]);
    float4 o = {a0 * inv + bv.x, a1 * inv + bv.y, a2 * inv + bv.z, a3 * inv + bv.w};
    *reinterpret_cast<float4*>(&out[(size_t)n * F_ALL + obase]) = o;
  }
}

extern "C" void kernel_launch(void* const* d_in, const int* in_sizes, int n_in,
                              void* d_out, int out_size, void* d_ws, size_t ws_size,
                              hipStream_t stream) {
  const float* x      = (const float*)d_in[0];
  const int*   row    = (const int*)d_in[1];
  const int*   col    = (const int*)d_in[2];
  const float* kern   = (const float*)d_in[3];
  const float* att_s  = (const float*)d_in[4];
  const float* att_n  = (const float*)d_in[5];
  const float* biases = (const float*)d_in[6];

  const int N = in_sizes[0] / F_IN;   // 100000
  const int E = in_sizes[1];          // 1600000

  // workspace: featb | xb | Wt | ws | wn | a_s | a_n | ptr   (~84 MB)
  unsigned short* featb = (unsigned short*)d_ws;
  unsigned short* xb    = featb + (size_t)N * F_ALL;
  unsigned short* Wt    = xb + (size_t)N * F_IN;
  float* ws  = (float*)(Wt + F_ALL * F_IN);
  float* wn  = ws + HEADS * F_IN;
  float* a_s = wn + HEADS * F_IN;
  float* a_n = a_s + (size_t)N * HEADS;
  int*   ptr = (int*)(a_n + (size_t)N * HEADS);
  float* out = (float*)d_out;

  hipLaunchKernelGGL(prep0, dim3((N + 1 + 255) / 256), dim3(256), 0, stream,
                     kern, att_s, att_n, row, Wt, ws, wn, ptr, N, E);
  hipLaunchKernelGGL(aproj_conv, dim3(2048), dim3(256), 0, stream,
                     x, ws, wn, xb, a_s, a_n, N);
  hipLaunchKernelGGL(feat_gemm_mfma, dim3((N + 63) / 64), dim3(256), 0, stream,
                     xb, Wt, featb, N);
  hipLaunchKernelGGL(gat_scatter, dim3((N + 1) / 2), dim3(256), 0, stream,
                     featb, a_s, a_n, col, ptr, biases, out, N);
}

// Round 11
// 271.640 us; speedup vs baseline: 1.0818x; 1.0818x over previous
//
#include <hip/hip_runtime.h>
#include <hip/hip_bf16.h>
#include <math.h>

// GAT forward: N=100000, E=1.6M (row sorted = dest), F_IN=128, F_OUT=32,
// HEADS=8, ALPHA=0.2. Output [N, 256] f32.
//
// Round 11 (request-structure test):
//  - gat_scatter rewritten: ONE wave per node, single fused pass.
//    4 groups x 16 lanes; group j owns cache line j of the feat row
//    (head pair 2j,2j+1). Per edge: 1 wave gather = 4 line transactions
//    (was 8x64B), a_n = 1 transaction (was 8x4B), col shfl-broadcast from
//    registers, sm accumulated in-loop (pass 1 eliminated), no parity
//    merge (lane owns 4 features exclusively).
//  - prep0 / aproj_conv / feat_gemm_mfma byte-identical to R10 (passed).

#define F_IN   128
#define F_ALL  256   // HEADS * F_OUT
#define HEADS  8
#define F_OUT  32
#define ALPHA  0.2f

using f32x4  = __attribute__((ext_vector_type(4))) float;
using bf16x8 = __attribute__((ext_vector_type(8))) short;

static __device__ __forceinline__ unsigned short f32_to_bf16(float f) {
  union { float f; unsigned u; } v; v.f = f;
  unsigned r = v.u + 0x7FFF + ((v.u >> 16) & 1);   // RNE
  return (unsigned short)(r >> 16);
}
static __device__ __forceinline__ unsigned cvt_pk_bf16(float lo, float hi) {
  unsigned r;
  asm("v_cvt_pk_bf16_f32 %0, %1, %2" : "=v"(r) : "v"(lo), "v"(hi));
  return r;
}
static __device__ __forceinline__ float bf16_lo(unsigned d) {
  return __uint_as_float(d << 16);
}
static __device__ __forceinline__ float bf16_hi(unsigned d) {
  return __uint_as_float(d & 0xffff0000u);
}

// ---- 0) prep0: ws/wn = W@att (f32), Wt[256][128] bf16, CSR ptr ----
__global__ __launch_bounds__(256) void prep0(const float* __restrict__ kern,
                                             const float* __restrict__ att_s,
                                             const float* __restrict__ att_n,
                                             const int* __restrict__ row,
                                             unsigned short* __restrict__ Wt,
                                             float* __restrict__ ws,
                                             float* __restrict__ wn,
                                             int* __restrict__ ptr,
                                             int N, int E) {
  int id = blockIdx.x * 256 + threadIdx.x;
  if (id < 2 * HEADS * F_IN) {      // ws[h][k], wn[h][k] (f32, exact)
    int which = id >> 10;
    int hk = id & 1023;
    int h = hk >> 7, k = hk & 127;
    const float* att = which ? att_n : att_s;
    float s = 0.f;
#pragma unroll
    for (int f = 0; f < F_OUT; ++f)
      s += kern[(size_t)h * (F_IN * F_OUT) + k * F_OUT + f] * att[h * F_OUT + f];
    (which ? wn : ws)[hk] = s;
  } else if (id < 4096) {           // Wt[c][k] = kern[c>>5][k][c&31], 16/thread
    int base = (id - 2048) * 16;
#pragma unroll
    for (int i = base; i < base + 16; ++i) {
      int c = i >> 7, k = i & 127;
      Wt[i] = f32_to_bf16(kern[(size_t)(c >> 5) * (F_IN * F_OUT) + k * F_OUT + (c & 31)]);
    }
  }
  if (id <= N) {                    // CSR offsets via binary search
    int lo = 0, hi = E;
    while (lo < hi) {
      int mid = (lo + hi) >> 1;
      if (row[mid] < id) lo = mid + 1; else hi = mid;
    }
    ptr[id] = lo;
  }
}

// ---- 1) aproj_conv: a_s/a_n (exact f32) + x->bf16, x read once ----
// wave per node: lane l = q*16+o; q = k-quarter (32 floats), o = output 0..15
__global__ __launch_bounds__(256) void aproj_conv(const float* __restrict__ x,
                                                  const float* __restrict__ ws,
                                                  const float* __restrict__ wn,
                                                  unsigned short* __restrict__ xb,
                                                  float* __restrict__ a_s,
                                                  float* __restrict__ a_n, int N) {
  const int t = threadIdx.x;
  const int l = t & 63;
  const int o = l & 15, q = l >> 4;
  const int wid = (blockIdx.x * 256 + t) >> 6;
  const int nw  = (gridDim.x * 256) >> 6;

  const float* wrow = (o < 8 ? ws + o * F_IN : wn + (o - 8) * F_IN) + q * 32;
  float4 wv[8];
#pragma unroll
  for (int i = 0; i < 8; i++) wv[i] = reinterpret_cast<const float4*>(wrow)[i];

  for (int n = wid; n < N; n += nw) {
    const float4* xr = reinterpret_cast<const float4*>(x + (size_t)n * F_IN + q * 32);
    float acc = 0.f;
#pragma unroll
    for (int i = 0; i < 8; i++) {
      float4 xv = xr[i];
      acc += xv.x * wv[i].x + xv.y * wv[i].y + xv.z * wv[i].z + xv.w * wv[i].w;
    }
    acc += __shfl_xor(acc, 16);
    acc += __shfl_xor(acc, 32);
    if (l < 16) {
      if (o < 8) a_s[n * HEADS + o] = acc;
      else       a_n[n * HEADS + (o - 8)] = acc;
    }
    // conversion: q==0 lanes own chunk o (32B, L1-hot after the dot loads)
    if (q == 0) {
      const float4* xc = reinterpret_cast<const float4*>(x + (size_t)n * F_IN + o * 8);
      float4 y0 = xc[0], y1 = xc[1];
      uint4 pk;
      pk.x = cvt_pk_bf16(y0.x, y0.y);
      pk.y = cvt_pk_bf16(y0.z, y0.w);
      pk.z = cvt_pk_bf16(y1.x, y1.y);
      pk.w = cvt_pk_bf16(y1.z, y1.w);
      *reinterpret_cast<uint4*>(xb + (size_t)n * F_IN + o * 8) = pk;
    }
  }
}

// ---- 2) feat = xb @ Wt^T via MFMA (swapped operands, packed stores) ----
__global__ __launch_bounds__(256) void feat_gemm_mfma(
    const unsigned short* __restrict__ xb,   // [N][128] bf16
    const unsigned short* __restrict__ Wt,   // [256][128] bf16
    unsigned short* __restrict__ featb,      // [N][256] bf16
    int N) {
  const int t  = threadIdx.x;
  const int w  = t >> 6;        // wave 0..3
  const int l  = t & 63;
  const int lr = l & 15;        // node within 16-tile (D col)
  const int lq = l >> 4;        // k-slice / D row group
  const int n0 = blockIdx.x * 64 + w * 16;

  f32x4 acc[16];
#pragma unroll
  for (int ct = 0; ct < 16; ++ct) acc[ct] = (f32x4){0.f, 0.f, 0.f, 0.f};

  int ar = n0 + lr; if (ar >= N) ar = N - 1;
  const unsigned short* xrow = xb + (size_t)ar * F_IN + lq * 8;
  bf16x8 xfr[4];
#pragma unroll
  for (int kc = 0; kc < 4; ++kc)
    xfr[kc] = *reinterpret_cast<const bf16x8*>(xrow + kc * 32);

#pragma unroll
  for (int ct = 0; ct < 16; ++ct) {
    const unsigned short* wrow = Wt + (size_t)(ct * 16 + lr) * F_IN + lq * 8;
#pragma unroll
    for (int kc = 0; kc < 4; ++kc) {
      bf16x8 wfr = *reinterpret_cast<const bf16x8*>(wrow + kc * 32);
      acc[ct] = __builtin_amdgcn_mfma_f32_16x16x32_bf16(wfr, xfr[kc], acc[ct], 0, 0, 0);
    }
  }
  // lane owns node ar, cols ct*16 + lq*4 + r: packed dwordx2 stores
  if (n0 + lr < N) {
    unsigned short* frow = featb + (size_t)ar * F_ALL + lq * 4;
#pragma unroll
    for (int ct = 0; ct < 16; ++ct) {
      uint2 v;
      v.x = cvt_pk_bf16(acc[ct][0], acc[ct][1]);
      v.y = cvt_pk_bf16(acc[ct][2], acc[ct][3]);
      *reinterpret_cast<uint2*>(frow + ct * 16) = v;
    }
  }
}

// ---- 3) per-node softmax + SpMM: ONE wave per node, single fused pass ----
// 4 groups x 16 lanes; group j owns line j (heads 2j, 2j+1).
// lane q (0..15): half q>>3 -> head h0 = 2j + (q>>3); 4 features per lane.
__global__ __launch_bounds__(256) void gat_scatter(
    const unsigned short* __restrict__ featb,
    const float* __restrict__ a_s, const float* __restrict__ a_n,
    const int* __restrict__ col, const int* __restrict__ ptr,
    const float* __restrict__ biases, float* __restrict__ out, int N) {
  const int t  = threadIdx.x;
  const int n  = blockIdx.x * 4 + (t >> 6);   // 4 nodes per block, wave/node
  if (n >= N) return;
  const int l  = t & 63;
  const int j  = l >> 4;                      // line group 0..3
  const int q  = l & 15;                      // lane within group
  const int h0 = 2 * j + (q >> 3);            // this lane's head
  const int obase = j * 64 + q * 4;           // 4 output features
  const size_t dbase = (size_t)j * 32 + q * 2; // dword offset in feat row

  const int start = ptr[n];
  const int deg   = ptr[n + 1] - start;

  const float4 bv = *reinterpret_cast<const float4*>(&biases[obase]);
  if (deg == 0) {
    *reinterpret_cast<float4*>(&out[(size_t)n * F_ALL + obase]) = bv;
    return;
  }

  const float as = a_s[n * HEADS + h0];
  const unsigned* fu32 = reinterpret_cast<const unsigned*>(featb);

  float a0 = 0.f, a1 = 0.f, a2 = 0.f, a3 = 0.f, sm = 0.f;

  if (deg <= 32) {
    // preload col into lanes 0..31 (lanes 32-63 mirror for width-32 shfl)
    const int le = l & 31;
    int creg = (le < deg) ? col[start + le] : 0;
#pragma unroll 4
    for (int e = 0; e < deg; ++e) {
      int c = __shfl(creg, e, 32);
      float an = a_n[c * HEADS + h0];
      float v = as + an;
      v = v > 0.f ? v : ALPHA * v;
      float w = __expf(v);
      sm += w;
      uint2 d = *reinterpret_cast<const uint2*>(fu32 + (size_t)c * 128 + dbase);
      a0 = fmaf(w, bf16_lo(d.x), a0);
      a1 = fmaf(w, bf16_hi(d.x), a1);
      a2 = fmaf(w, bf16_lo(d.y), a2);
      a3 = fmaf(w, bf16_hi(d.y), a3);
    }
  } else {
    // rare deg>32: same body, col loaded per edge (uniform broadcast)
    for (int e = 0; e < deg; ++e) {
      int c = col[start + e];
      float an = a_n[c * HEADS + h0];
      float v = as + an;
      v = v > 0.f ? v : ALPHA * v;
      float w = __expf(v);
      sm += w;
      uint2 d = *reinterpret_cast<const uint2*>(fu32 + (size_t)c * 128 + dbase);
      a0 = fmaf(w, bf16_lo(d.x), a0);
      a1 = fmaf(w, bf16_hi(d.x), a1);
      a2 = fmaf(w, bf16_lo(d.y), a2);
      a3 = fmaf(w, bf16_hi(d.y), a3);
    }
  }

  const float inv = 1.0f / sm;
  float4 o = {a0 * inv + bv.x, a1 * inv + bv.y, a2 * inv + bv.z, a3 * inv + bv.w};
  *reinterpret_cast<float4*>(&out[(size_t)n * F_ALL + obase]) = o;
}

extern "C" void kernel_launch(void* const* d_in, const int* in_sizes, int n_in,
                              void* d_out, int out_size, void* d_ws, size_t ws_size,
                              hipStream_t stream) {
  const float* x      = (const float*)d_in[0];
  const int*   row    = (const int*)d_in[1];
  const int*   col    = (const int*)d_in[2];
  const float* kern   = (const float*)d_in[3];
  const float* att_s  = (const float*)d_in[4];
  const float* att_n  = (const float*)d_in[5];
  const float* biases = (const float*)d_in[6];

  const int N = in_sizes[0] / F_IN;   // 100000
  const int E = in_sizes[1];          // 1600000

  // workspace: featb | xb | Wt | ws | wn | a_s | a_n | ptr   (~84 MB)
  unsigned short* featb = (unsigned short*)d_ws;
  unsigned short* xb    = featb + (size_t)N * F_ALL;
  unsigned short* Wt    = xb + (size_t)N * F_IN;
  float* ws  = (float*)(Wt + F_ALL * F_IN);
  float* wn  = ws + HEADS * F_IN;
  float* a_s = wn + HEADS * F_IN;
  float* a_n = a_s + (size_t)N * HEADS;
  int*   ptr = (int*)(a_n + (size_t)N * HEADS);
  float* out = (float*)d_out;

  hipLaunchKernelGGL(prep0, dim3((N + 1 + 255) / 256), dim3(256), 0, stream,
                     kern, att_s, att_n, row, Wt, ws, wn, ptr, N, E);
  hipLaunchKernelGGL(aproj_conv, dim3(2048), dim3(256), 0, stream,
                     x, ws, wn, xb, a_s, a_n, N);
  hipLaunchKernelGGL(feat_gemm_mfma, dim3((N + 63) / 64), dim3(256), 0, stream,
                     xb, Wt, featb, N);
  hipLaunchKernelGGL(gat_scatter, dim3((N + 3) / 4), dim3(256), 0, stream,
                     featb, a_s, a_n, col, ptr, biases, out, N);
}